// Round 2
// baseline (1276.184 us; speedup 1.0000x reference)
//
#include <hip/hip_runtime.h>
#include <hip/hip_bf16.h>
#include <stdint.h>

#define IN_F   4096
#define OUT_F  11008
#define NG     32

typedef __bf16 bf16_t;
typedef __bf16 bf16x8 __attribute__((ext_vector_type(8)));
typedef float  f32x4  __attribute__((ext_vector_type(4)));
typedef float  f32x16 __attribute__((ext_vector_type(16)));

// ---------------- kernel 1: xs[m,k] = bf16(x[m,k] * input_scale[k]) ----------------
__global__ __launch_bounds__(256) void scale_cast_kernel(
    const float* __restrict__ x, const float* __restrict__ iscale,
    bf16_t* __restrict__ xs)
{
    size_t idx = ((size_t)blockIdx.x * 256 + threadIdx.x) * 8;
    const float4 a0 = *(const float4*)(x + idx);
    const float4 a1 = *(const float4*)(x + idx + 4);
    const int k = (int)(idx & (IN_F - 1));
    const float4 s0 = *(const float4*)(iscale + k);
    const float4 s1 = *(const float4*)(iscale + k + 4);
    bf16x8 o;
    o[0] = (bf16_t)(a0.x * s0.x);
    o[1] = (bf16_t)(a0.y * s0.y);
    o[2] = (bf16_t)(a0.z * s0.z);
    o[3] = (bf16_t)(a0.w * s0.w);
    o[4] = (bf16_t)(a1.x * s1.x);
    o[5] = (bf16_t)(a1.y * s1.y);
    o[6] = (bf16_t)(a1.z * s1.z);
    o[7] = (bf16_t)(a1.w * s1.w);
    *(bf16x8*)(xs + idx) = o;
}

// ---------------- kernel 2: W[n,k] = bf16((q - zero[n,g]) * scale[n,g]) ------------
__global__ __launch_bounds__(256) void dequant_kernel(
    const int* __restrict__ qw, const float* __restrict__ scales,
    const float* __restrict__ zeros, bf16_t* __restrict__ wq)
{
    const size_t tid = (size_t)blockIdx.x * 256 + threadIdx.x;
    const int4 q = *(const int4*)(qw + tid * 4);
    const size_t jj = tid * 4;
    const int n = (int)(jj >> 11);
    const int j = (int)(jj & 2047);
    const int g = j >> 6;
    const float s = scales[n * NG + g];
    const float z = zeros[n * NG + g];
    bf16x8 o;
    o[0] = (bf16_t)(((float)((q.x >> 4) & 15) - z) * s);
    o[1] = (bf16_t)(((float)( q.x       & 15) - z) * s);
    o[2] = (bf16_t)(((float)((q.y >> 4) & 15) - z) * s);
    o[3] = (bf16_t)(((float)( q.y       & 15) - z) * s);
    o[4] = (bf16_t)(((float)((q.z >> 4) & 15) - z) * s);
    o[5] = (bf16_t)(((float)( q.z       & 15) - z) * s);
    o[6] = (bf16_t)(((float)((q.w >> 4) & 15) - z) * s);
    o[7] = (bf16_t)(((float)( q.w       & 15) - z) * s);
    *(bf16x8*)(wq + (size_t)n * IN_F + 2 * j) = o;
}

// ---------------- kernel 3: 256x256-tile 8-phase pipelined GEMM --------------------
// R2 change: MFMA shape 16x16x32 -> 32x32x16 (2495 vs ~2176 TF ceiling, half the
// MFMA instruction count). Staging side (layout, piece swizzle, GLL pattern, vmcnt
// schedule) is IDENTICAL to R1. Only fragment reads, MFMA bodies, epilogue change.
//
// Per-wave tile 128x64 as 4(m) x 2(n) frags of 32x32; K=16 per MFMA -> 2 MFMA per
// frag-pair per 32-k slot. Per phase: 8 MFMA (one m-group = 2 mi).
// A/B frag layout (gfx950 2xK convention): row/col = lane&31, k = (lane>>5)*8 + i.
// C/D layout (m74/m101-verified): col = lane&31, row = (reg&3)+8*(reg>>2)+4*(lane>>5).
// Read swizzle: piece p = h*2 + (lane>>5) of row r stored at slot (p + (r>>1))&3;
// per-thread this collapses to elem-offset off0 = ((lane>>5)+((lane&31)>>1)&3)*8 for
// h=0 and off0^16 for h=1 (independent of mi/nj/wm/wn since those are ≡0 mod 4 rows).
// Conflict check: each 4-bank group receives exactly 8 of 64 lanes -> minimal 8
// bank-cycles per b128, conflict-free.

#define GLL(src, dst) __builtin_amdgcn_global_load_lds( \
    (const __attribute__((address_space(1))) void*)(src), \
    (__attribute__((address_space(3))) void*)(dst), 16, 0, 0)

#define STAGE_A(co, sl) { GLL(aS0 + (co), aD0 + (sl)*8192); GLL(aS1 + (co), aD1 + (sl)*8192); }
#define STAGE_B(co, sl) { GLL(bS0 + (co), bD0 + (sl)*8192); GLL(bS1 + (co), bD1 + (sl)*8192); }

// af[0]=mi(2mg+0),h0  af[1]=mi(2mg+0),h1  af[2]=mi(2mg+1),h0  af[3]=mi(2mg+1),h1
#define LDA32(sl, mg) { const bf16_t* ap_ = As + (sl)*8192 + (mg)*2048 + aB2; \
    af[0] = *(const bf16x8*)(ap_ + aoff0);        af[1] = *(const bf16x8*)(ap_ + aoff1); \
    af[2] = *(const bf16x8*)(ap_ + 1024 + aoff0); af[3] = *(const bf16x8*)(ap_ + 1024 + aoff1); }
// bf[0]=nj0,h0  bf[1]=nj0,h1  bf[2]=nj1,h0  bf[3]=nj1,h1
#define LDB32(sl) { const bf16_t* bp_ = Bs + (sl)*8192 + bB2; \
    bf[0] = *(const bf16x8*)(bp_ + aoff0);        bf[1] = *(const bf16x8*)(bp_ + aoff1); \
    bf[2] = *(const bf16x8*)(bp_ + 1024 + aoff0); bf[3] = *(const bf16x8*)(bp_ + 1024 + aoff1); }

// 8 MFMA: h=0 wave (4 independent), then h=1 wave (dep distance 4)
#define MFMA8(mg) { \
    __builtin_amdgcn_s_setprio(1); \
    acc[2*(mg)+0][0] = __builtin_amdgcn_mfma_f32_32x32x16_bf16(af[0], bf[0], acc[2*(mg)+0][0], 0,0,0); \
    acc[2*(mg)+0][1] = __builtin_amdgcn_mfma_f32_32x32x16_bf16(af[0], bf[2], acc[2*(mg)+0][1], 0,0,0); \
    acc[2*(mg)+1][0] = __builtin_amdgcn_mfma_f32_32x32x16_bf16(af[2], bf[0], acc[2*(mg)+1][0], 0,0,0); \
    acc[2*(mg)+1][1] = __builtin_amdgcn_mfma_f32_32x32x16_bf16(af[2], bf[2], acc[2*(mg)+1][1], 0,0,0); \
    acc[2*(mg)+0][0] = __builtin_amdgcn_mfma_f32_32x32x16_bf16(af[1], bf[1], acc[2*(mg)+0][0], 0,0,0); \
    acc[2*(mg)+0][1] = __builtin_amdgcn_mfma_f32_32x32x16_bf16(af[1], bf[3], acc[2*(mg)+0][1], 0,0,0); \
    acc[2*(mg)+1][0] = __builtin_amdgcn_mfma_f32_32x32x16_bf16(af[3], bf[1], acc[2*(mg)+1][0], 0,0,0); \
    acc[2*(mg)+1][1] = __builtin_amdgcn_mfma_f32_32x32x16_bf16(af[3], bf[3], acc[2*(mg)+1][1], 0,0,0); \
    __builtin_amdgcn_s_setprio(0); }

#define BAR() __builtin_amdgcn_s_barrier()
#define WAITV(n) asm volatile("s_waitcnt vmcnt(" #n ")" ::: "memory")

__global__ __launch_bounds__(512, 2) void gemm_bt_kernel(
    const bf16_t* __restrict__ A,   // [M, K]
    const bf16_t* __restrict__ B,   // [N, K]
    const float* __restrict__ bias, // [N]
    float* __restrict__ C)          // [M, N]
{
    constexpr int K = IN_F;
    constexpr int N = OUT_F;
    constexpr int NXB = N / 256;    // 43

    __shared__ bf16_t As[4 * 8192]; // 64 KB
    __shared__ bf16_t Bs[4 * 8192]; // 64 KB

    // T1: XCD-aware bijective swizzle (grid = 1376, 1376 % 8 == 0)
    const int nwg = gridDim.x;
    const int cpx = nwg >> 3;
    const int bid = blockIdx.x;
    const int sw  = (bid & 7) * cpx + (bid >> 3);
    const int bx = sw % NXB, by = sw / NXB;
    const int m0 = by * 256, n0 = bx * 256;

    const int t    = threadIdx.x;
    const int lane = t & 63;
    const int wave = t >> 6;
    const int wm = wave >> 2;       // 0..1
    const int wn = wave & 3;        // 0..3

    // --- staging addresses (IDENTICAL to R1) ---
    const int r0 = t >> 2;
    const int p0 = ((t & 3) - ((t >> 3) & 3)) & 3;
    const bf16_t* aS0 = A + (size_t)(m0 + r0) * K + p0 * 8;
    const bf16_t* aS1 = aS0 + (size_t)128 * K;
    const bf16_t* bS0 = B + (size_t)(n0 + r0) * K + p0 * 8;
    const bf16_t* bS1 = bS0 + (size_t)128 * K;
    bf16_t* aD0 = As + t * 8;
    bf16_t* aD1 = As + (512 + t) * 8;
    bf16_t* bD0 = Bs + t * 8;
    bf16_t* bD1 = Bs + (512 + t) * 8;

    // --- compute-side read bases for 32x32 frags ---
    const int r31 = lane & 31;
    const int kg  = lane >> 5;                       // k-group (which 8-k window)
    const int aB2 = wm * 4096 + r31 * 32;            // + mg*2048 + mi-local*1024 + slot*8192
    const int bB2 = wn * 2048 + r31 * 32;            // + nj*1024 + slot*8192
    const int aoff0 = ((kg + (r31 >> 1)) & 3) * 8;   // h=0 piece slot
    const int aoff1 = aoff0 ^ 16;                    // h=1 piece slot (s+2 mod 4)

    f32x16 acc[4][2] = {};
    bf16x8 af[4], bf[4];

    // --- prologue: stage tile0 (k0->slot0, k1->slot1) + tile1-k0 (slot2) ---
    STAGE_A(0,  0); STAGE_B(0,  0);
    STAGE_A(32, 1); STAGE_B(32, 1);
    STAGE_A(64, 2); STAGE_B(64, 2);
    WAITV(8);
    BAR();

    // --- main loop: iterations 0..30; iteration tt covers tiles T=2tt, T+1 ---
    for (int tt = 0; tt < 31; ++tt) {
        // ph1: even tile, k-slice 0, m-group 0 | stage A-k1(T+1) -> slot3
        LDA32(0, 0); LDB32(0);
        STAGE_A(96, 3);
        BAR(); MFMA8(0); BAR();
        // ph2: k0, mg1 | stage B-k1(T+1) -> slot3 | wait guards ph3 (slot1)
        LDA32(0, 1);
        STAGE_B(96, 3);
        WAITV(8); BAR(); MFMA8(1); BAR();
        // ph3: k1 (slot1), mg0 | stage A-k0(T+2) -> slot0
        LDA32(1, 0); LDB32(1);
        STAGE_A(128, 0);
        BAR(); MFMA8(0); BAR();
        // ph4: k1, mg1 | stage B-k0(T+2) -> slot0 | wait guards ph5 (slot2)
        LDA32(1, 1);
        STAGE_B(128, 0);
        WAITV(8); BAR(); MFMA8(1); BAR();
        // ph5: odd tile T+1, k0 (slot2), mg0 | stage A-k1(T+2) -> slot1
        LDA32(2, 0); LDB32(2);
        STAGE_A(160, 1);
        BAR(); MFMA8(0); BAR();
        // ph6 | stage B-k1(T+2) -> slot1 | wait guards ph7 (slot3)
        LDA32(2, 1);
        STAGE_B(160, 1);
        WAITV(8); BAR(); MFMA8(1); BAR();
        // ph7: k1 (slot3), mg0 | stage A-k0(T+3) -> slot2
        LDA32(3, 0); LDB32(3);
        STAGE_A(192, 2);
        BAR(); MFMA8(0); BAR();
        // ph8 | stage B-k0(T+3) -> slot2 | wait guards next ph1 (slot0)
        LDA32(3, 1);
        STAGE_B(192, 2);
        WAITV(8); BAR(); MFMA8(1); BAR();

        aS0 += 128; aS1 += 128; bS0 += 128; bS1 += 128;
    }

    // --- peeled last iteration (tiles 62,63) ---
    LDA32(0, 0); LDB32(0);
    STAGE_A(96, 3);
    BAR(); MFMA8(0); BAR();
    LDA32(0, 1);
    STAGE_B(96, 3);
    WAITV(8); BAR(); MFMA8(1); BAR();
    LDA32(1, 0); LDB32(1);
    BAR(); MFMA8(0); BAR();
    LDA32(1, 1);
    WAITV(4); BAR(); MFMA8(1); BAR();
    LDA32(2, 0); LDB32(2);
    BAR(); MFMA8(0); BAR();
    LDA32(2, 1);
    WAITV(0); BAR(); MFMA8(1); BAR();
    LDA32(3, 0); LDB32(3);
    BAR(); MFMA8(0); BAR();
    LDA32(3, 1);
    BAR(); MFMA8(1);

    // --- epilogue: 32x32 C/D layout col=lane&31, row=(reg&3)+8*(reg>>2)+4*(lane>>5)
    const int cn = r31;
    const int rb = kg * 4;
    #pragma unroll
    for (int nj = 0; nj < 2; ++nj) {
        const int col = n0 + wn * 64 + nj * 32 + cn;
        const float bj = bias[col];
        #pragma unroll
        for (int mi = 0; mi < 4; ++mi) {
            const int rowb = m0 + wm * 128 + mi * 32 + rb;
            float* cp = C + (size_t)rowb * N + col;
            #pragma unroll
            for (int reg = 0; reg < 16; ++reg) {
                const int roff = (reg & 3) + 8 * (reg >> 2);
                cp[(size_t)roff * N] = acc[mi][nj][reg] + bj;
            }
        }
    }
}

// ---------------- launch ----------------
extern "C" void kernel_launch(void* const* d_in, const int* in_sizes, int n_in,
                              void* d_out, int out_size, void* d_ws, size_t ws_size,
                              hipStream_t stream)
{
    const float* x      = (const float*)d_in[0];   // [4,2048,4096] f32
    const int*   qw     = (const int*)d_in[1];     // [11008,2048] i32 (byte vals)
    const float* scales = (const float*)d_in[2];   // [11008,32]
    const float* zeros  = (const float*)d_in[3];   // [11008,32]
    const float* iscale = (const float*)d_in[4];   // [4096]
    const float* bias   = (const float*)d_in[5];   // [11008]
    float* out = (float*)d_out;                    // [4,2048,11008] f32

    const int M = in_sizes[0] / IN_F;              // 8192

    bf16_t* xs = (bf16_t*)d_ws;
    bf16_t* wq = (bf16_t*)((char*)d_ws + (size_t)M * IN_F * sizeof(bf16_t));

    scale_cast_kernel<<<(M * IN_F) / 2048, 256, 0, stream>>>(x, iscale, xs);
    dequant_kernel<<<(OUT_F * (IN_F / 2)) / 1024, 256, 0, stream>>>(qw, scales, zeros, wq);

    const int nblocks = (M / 256) * (OUT_F / 256); // 32*43 = 1376 (== 0 mod 8)
    gemm_bt_kernel<<<nblocks, 512, 0, stream>>>(xs, wq, bias, out);
}

// Round 3
// 1233.234 us; speedup vs baseline: 1.0348x; 1.0348x over previous
//
#include <hip/hip_runtime.h>
#include <hip/hip_bf16.h>
#include <stdint.h>

#define IN_F   4096
#define OUT_F  11008
#define NG     32

typedef __bf16 bf16_t;
typedef __bf16 bf16x8 __attribute__((ext_vector_type(8)));
typedef float  f32x4  __attribute__((ext_vector_type(4)));

// ---------------- merged prep kernel: scale_cast (blocks < nbScale) + dequant -------
// part 1: xs[m,k] = bf16(x[m,k] * input_scale[k])
// part 2: wq[n,k] = bf16((q - zero[n,g]) * scale[n,g]), high nibble first
__global__ __launch_bounds__(256) void prep_kernel(
    const float* __restrict__ x, const float* __restrict__ iscale,
    bf16_t* __restrict__ xs,
    const int* __restrict__ qw, const float* __restrict__ scales,
    const float* __restrict__ zeros, bf16_t* __restrict__ wq,
    int nbScale)
{
    if ((int)blockIdx.x < nbScale) {
        size_t idx = ((size_t)blockIdx.x * 256 + threadIdx.x) * 8;
        const float4 a0 = *(const float4*)(x + idx);
        const float4 a1 = *(const float4*)(x + idx + 4);
        const int k = (int)(idx & (IN_F - 1));
        const float4 s0 = *(const float4*)(iscale + k);
        const float4 s1 = *(const float4*)(iscale + k + 4);
        bf16x8 o;
        o[0] = (bf16_t)(a0.x * s0.x);
        o[1] = (bf16_t)(a0.y * s0.y);
        o[2] = (bf16_t)(a0.z * s0.z);
        o[3] = (bf16_t)(a0.w * s0.w);
        o[4] = (bf16_t)(a1.x * s1.x);
        o[5] = (bf16_t)(a1.y * s1.y);
        o[6] = (bf16_t)(a1.z * s1.z);
        o[7] = (bf16_t)(a1.w * s1.w);
        *(bf16x8*)(xs + idx) = o;
    } else {
        const size_t tid = (size_t)(blockIdx.x - nbScale) * 256 + threadIdx.x;
        const int4 q = *(const int4*)(qw + tid * 4);
        const size_t jj = tid * 4;
        const int n = (int)(jj >> 11);
        const int j = (int)(jj & 2047);
        const int g = j >> 6;
        const float s = scales[n * NG + g];
        const float z = zeros[n * NG + g];
        bf16x8 o;
        o[0] = (bf16_t)(((float)((q.x >> 4) & 15) - z) * s);
        o[1] = (bf16_t)(((float)( q.x       & 15) - z) * s);
        o[2] = (bf16_t)(((float)((q.y >> 4) & 15) - z) * s);
        o[3] = (bf16_t)(((float)( q.y       & 15) - z) * s);
        o[4] = (bf16_t)(((float)((q.z >> 4) & 15) - z) * s);
        o[5] = (bf16_t)(((float)( q.z       & 15) - z) * s);
        o[6] = (bf16_t)(((float)((q.w >> 4) & 15) - z) * s);
        o[7] = (bf16_t)(((float)( q.w       & 15) - z) * s);
        *(bf16x8*)(wq + (size_t)n * IN_F + 2 * j) = o;
    }
}

// ---------------- kernel 3: 256x256-tile 8-phase pipelined GEMM (R1 structure) -----
// C[M,N] = A[M,K] * B[N,K]^T + bias.  BK=64 as two 32-k half-tiles per operand.
// MFMA 16x16x32 (R2's 32x32x16 experiment: isomorphic static bank pattern but
// measured +4 conflict-cycles per ds_read_b128, 67M total -> reverted).
// LDS: A = 4 half-slots x [256 rows][32 k] bf16 (16 KB each) = 64 KB; B same; 128 KB.
// Slot ring: K-tile t, k-slice s -> slot (2t+s)&3. 8 waves (2M x 4N), 512 thr.
// Counted waits: vmcnt(8) keeps 4 newest half-tile stages in flight; the half the
// next phase reads has landed. Piece-swizzle: row r (64B = 4x16B pieces) stores
// logical piece p at slot (p + (r>>1))&3; applied on the global-read side of
// global_load_lds; read side uses sp = (fq + (fm>>1))&3 -> measured 0 conflicts.
// R3 change: epilogue uses nontemporal stores (C is 360 MB write-once).

#define GLL(src, dst) __builtin_amdgcn_global_load_lds( \
    (const __attribute__((address_space(1))) void*)(src), \
    (__attribute__((address_space(3))) void*)(dst), 16, 0, 0)

#define STAGE_A(co, sl) { GLL(aS0 + (co), aD0 + (sl)*8192); GLL(aS1 + (co), aD1 + (sl)*8192); }
#define STAGE_B(co, sl) { GLL(bS0 + (co), bD0 + (sl)*8192); GLL(bS1 + (co), bD1 + (sl)*8192); }

#define LDA(sl, mg) { const bf16_t* ap_ = As + (sl)*8192 + (mg)*2048 + aRd; \
    af[0] = *(const bf16x8*)(ap_);        af[1] = *(const bf16x8*)(ap_ + 512); \
    af[2] = *(const bf16x8*)(ap_ + 1024); af[3] = *(const bf16x8*)(ap_ + 1536); }
#define LDB(sl) { const bf16_t* bp_ = Bs + (sl)*8192 + bRd; \
    bf[0] = *(const bf16x8*)(bp_);        bf[1] = *(const bf16x8*)(bp_ + 512); \
    bf[2] = *(const bf16x8*)(bp_ + 1024); bf[3] = *(const bf16x8*)(bp_ + 1536); }

#define MFMA16(mg) { \
    __builtin_amdgcn_s_setprio(1); \
    acc[4*(mg)+0][0] = __builtin_amdgcn_mfma_f32_16x16x32_bf16(af[0], bf[0], acc[4*(mg)+0][0], 0,0,0); \
    acc[4*(mg)+0][1] = __builtin_amdgcn_mfma_f32_16x16x32_bf16(af[0], bf[1], acc[4*(mg)+0][1], 0,0,0); \
    acc[4*(mg)+0][2] = __builtin_amdgcn_mfma_f32_16x16x32_bf16(af[0], bf[2], acc[4*(mg)+0][2], 0,0,0); \
    acc[4*(mg)+0][3] = __builtin_amdgcn_mfma_f32_16x16x32_bf16(af[0], bf[3], acc[4*(mg)+0][3], 0,0,0); \
    acc[4*(mg)+1][0] = __builtin_amdgcn_mfma_f32_16x16x32_bf16(af[1], bf[0], acc[4*(mg)+1][0], 0,0,0); \
    acc[4*(mg)+1][1] = __builtin_amdgcn_mfma_f32_16x16x32_bf16(af[1], bf[1], acc[4*(mg)+1][1], 0,0,0); \
    acc[4*(mg)+1][2] = __builtin_amdgcn_mfma_f32_16x16x32_bf16(af[1], bf[2], acc[4*(mg)+1][2], 0,0,0); \
    acc[4*(mg)+1][3] = __builtin_amdgcn_mfma_f32_16x16x32_bf16(af[1], bf[3], acc[4*(mg)+1][3], 0,0,0); \
    acc[4*(mg)+2][0] = __builtin_amdgcn_mfma_f32_16x16x32_bf16(af[2], bf[0], acc[4*(mg)+2][0], 0,0,0); \
    acc[4*(mg)+2][1] = __builtin_amdgcn_mfma_f32_16x16x32_bf16(af[2], bf[1], acc[4*(mg)+2][1], 0,0,0); \
    acc[4*(mg)+2][2] = __builtin_amdgcn_mfma_f32_16x16x32_bf16(af[2], bf[2], acc[4*(mg)+2][2], 0,0,0); \
    acc[4*(mg)+2][3] = __builtin_amdgcn_mfma_f32_16x16x32_bf16(af[2], bf[3], acc[4*(mg)+2][3], 0,0,0); \
    acc[4*(mg)+3][0] = __builtin_amdgcn_mfma_f32_16x16x32_bf16(af[3], bf[0], acc[4*(mg)+3][0], 0,0,0); \
    acc[4*(mg)+3][1] = __builtin_amdgcn_mfma_f32_16x16x32_bf16(af[3], bf[1], acc[4*(mg)+3][1], 0,0,0); \
    acc[4*(mg)+3][2] = __builtin_amdgcn_mfma_f32_16x16x32_bf16(af[3], bf[2], acc[4*(mg)+3][2], 0,0,0); \
    acc[4*(mg)+3][3] = __builtin_amdgcn_mfma_f32_16x16x32_bf16(af[3], bf[3], acc[4*(mg)+3][3], 0,0,0); \
    __builtin_amdgcn_s_setprio(0); }

#define BAR() __builtin_amdgcn_s_barrier()
#define WAITV(n) asm volatile("s_waitcnt vmcnt(" #n ")" ::: "memory")

__global__ __launch_bounds__(512, 2) void gemm_bt_kernel(
    const bf16_t* __restrict__ A,   // [M, K]
    const bf16_t* __restrict__ B,   // [N, K]
    const float* __restrict__ bias, // [N]
    float* __restrict__ C)          // [M, N]
{
    constexpr int K = IN_F;
    constexpr int N = OUT_F;
    constexpr int NXB = N / 256;    // 43

    __shared__ bf16_t As[4 * 8192]; // 64 KB
    __shared__ bf16_t Bs[4 * 8192]; // 64 KB

    // T1: XCD-aware bijective swizzle (grid = 1376, 1376 % 8 == 0)
    const int nwg = gridDim.x;
    const int cpx = nwg >> 3;
    const int bid = blockIdx.x;
    const int sw  = (bid & 7) * cpx + (bid >> 3);
    const int bx = sw % NXB, by = sw / NXB;
    const int m0 = by * 256, n0 = bx * 256;

    const int t    = threadIdx.x;
    const int lane = t & 63;
    const int wave = t >> 6;
    const int wm = wave >> 2;       // 0..1
    const int wn = wave & 3;        // 0..3
    const int fm = lane & 15;
    const int fq = lane >> 4;

    // --- staging addresses ---
    const int r0 = t >> 2;
    const int p0 = ((t & 3) - ((t >> 3) & 3)) & 3;
    const bf16_t* aS0 = A + (size_t)(m0 + r0) * K + p0 * 8;
    const bf16_t* aS1 = aS0 + (size_t)128 * K;
    const bf16_t* bS0 = B + (size_t)(n0 + r0) * K + p0 * 8;
    const bf16_t* bS1 = bS0 + (size_t)128 * K;
    bf16_t* aD0 = As + t * 8;           // + slot*8192 at use
    bf16_t* aD1 = As + (512 + t) * 8;
    bf16_t* bD0 = Bs + t * 8;
    bf16_t* bD1 = Bs + (512 + t) * 8;

    // --- compute-side read bases (piece slot constant per thread) ---
    const int sp  = (fq + (fm >> 1)) & 3;
    const int aRd = wm * 4096 + fm * 32 + sp * 8;   // + mg*2048 + i*512 + slot*8192
    const int bRd = wn * 2048 + fm * 32 + sp * 8;   // + j*512 + slot*8192

    f32x4  acc[8][4] = {};
    bf16x8 af[4], bf[4];

    // --- prologue: stage tile0 (k0->slot0, k1->slot1) + tile1-k0 (slot2) ---
    STAGE_A(0,  0); STAGE_B(0,  0);
    STAGE_A(32, 1); STAGE_B(32, 1);
    STAGE_A(64, 2); STAGE_B(64, 2);
    WAITV(8);       // tile0-k0 (A+B) landed; 4 stages in flight
    BAR();

    // --- main loop: iterations 0..30; iteration tt covers tiles T=2tt, T+1 ---
    for (int tt = 0; tt < 31; ++tt) {
        // ph1: even tile, k-slice 0, M-group 0 | stage A-k1(T+1) -> slot3
        LDA(0, 0); LDB(0);
        STAGE_A(96, 3);
        BAR(); MFMA16(0); BAR();
        // ph2: k0, mg1 | stage B-k1(T+1) -> slot3 | wait guards ph3 (slot1)
        LDA(0, 1);
        STAGE_B(96, 3);
        WAITV(8); BAR(); MFMA16(1); BAR();
        // ph3: k1 (slot1), mg0 | stage A-k0(T+2) -> slot0 (readers done at ph2-end)
        LDA(1, 0); LDB(1);
        STAGE_A(128, 0);
        BAR(); MFMA16(0); BAR();
        // ph4: k1, mg1 | stage B-k0(T+2) -> slot0 | wait guards ph5 (slot2)
        LDA(1, 1);
        STAGE_B(128, 0);
        WAITV(8); BAR(); MFMA16(1); BAR();
        // ph5: odd tile T+1, k0 (slot2), mg0 | stage A-k1(T+2) -> slot1
        LDA(2, 0); LDB(2);
        STAGE_A(160, 1);
        BAR(); MFMA16(0); BAR();
        // ph6 | stage B-k1(T+2) -> slot1 | wait guards ph7 (slot3)
        LDA(2, 1);
        STAGE_B(160, 1);
        WAITV(8); BAR(); MFMA16(1); BAR();
        // ph7: k1 (slot3), mg0 | stage A-k0(T+3) -> slot2
        LDA(3, 0); LDB(3);
        STAGE_A(192, 2);
        BAR(); MFMA16(0); BAR();
        // ph8 | stage B-k0(T+3) -> slot2 | wait guards next ph1 (slot0)
        LDA(3, 1);
        STAGE_B(192, 2);
        WAITV(8); BAR(); MFMA16(1); BAR();

        aS0 += 128; aS1 += 128; bS0 += 128; bS1 += 128;
    }

    // --- peeled last iteration (tiles 62,63) ---
    LDA(0, 0); LDB(0);
    STAGE_A(96, 3);
    BAR(); MFMA16(0); BAR();
    LDA(0, 1);
    STAGE_B(96, 3);
    WAITV(8); BAR(); MFMA16(1); BAR();     // guards slot1 (staged 2 iters back)
    LDA(1, 0); LDB(1);
    BAR(); MFMA16(0); BAR();
    LDA(1, 1);
    WAITV(4); BAR(); MFMA16(1); BAR();     // guards slot2 (only 2 stages newer)
    LDA(2, 0); LDB(2);
    BAR(); MFMA16(0); BAR();
    LDA(2, 1);
    WAITV(0); BAR(); MFMA16(1); BAR();     // guards slot3 (nothing newer)
    LDA(3, 0); LDB(3);
    BAR(); MFMA16(0); BAR();
    LDA(3, 1);
    BAR(); MFMA16(1);

    // --- epilogue: C/D layout col=lane&15, row=(lane>>4)*4+reg (m89/m91) ---
    // nontemporal: C is written once, never re-read -> don't evict A/B from L2.
    const int cn = lane & 15;
    const int cm = (lane >> 4) * 4;
    #pragma unroll
    for (int j = 0; j < 4; ++j) {
        const int col = n0 + wn * 64 + j * 16 + cn;
        const float bj = bias[col];
        #pragma unroll
        for (int i = 0; i < 8; ++i) {
            const int row = m0 + wm * 128 + i * 16 + cm;
            float* cp = C + (size_t)row * N + col;
            #pragma unroll
            for (int r = 0; r < 4; ++r)
                __builtin_nontemporal_store(acc[i][j][r] + bj, cp + (size_t)r * N);
        }
    }
}

// ---------------- launch ----------------
extern "C" void kernel_launch(void* const* d_in, const int* in_sizes, int n_in,
                              void* d_out, int out_size, void* d_ws, size_t ws_size,
                              hipStream_t stream)
{
    const float* x      = (const float*)d_in[0];   // [4,2048,4096] f32
    const int*   qw     = (const int*)d_in[1];     // [11008,2048] i32 (byte vals)
    const float* scales = (const float*)d_in[2];   // [11008,32]
    const float* zeros  = (const float*)d_in[3];   // [11008,32]
    const float* iscale = (const float*)d_in[4];   // [4096]
    const float* bias   = (const float*)d_in[5];   // [11008]
    float* out = (float*)d_out;                    // [4,2048,11008] f32

    const int M = in_sizes[0] / IN_F;              // 8192

    bf16_t* xs = (bf16_t*)d_ws;
    bf16_t* wq = (bf16_t*)((char*)d_ws + (size_t)M * IN_F * sizeof(bf16_t));

    // merged prep: scale_cast (nbScale blocks) + dequant (22016 blocks)
    const int nbScale = (M * IN_F) / 2048;                     // 16384
    const int nbDeq   = (OUT_F * (IN_F / 2)) / 1024;           // 22016
    prep_kernel<<<nbScale + nbDeq, 256, 0, stream>>>(
        x, iscale, xs, qw, scales, zeros, wq, nbScale);

    const int nblocks = (M / 256) * (OUT_F / 256); // 32*43 = 1376 (== 0 mod 8)
    gemm_bt_kernel<<<nblocks, 512, 0, stream>>>(xs, wq, bias, out);
}